// Round 6
// baseline (301.158 us; speedup 1.0000x reference)
//
#include <hip/hip_runtime.h>
#include <stdint.h>
#include <stddef.h>

typedef unsigned short u16;
typedef unsigned int u32;
typedef float f32x4 __attribute__((ext_vector_type(4)));
typedef __bf16 bf16x8 __attribute__((ext_vector_type(8)));
typedef uint32_t u32x4 __attribute__((ext_vector_type(4)));
typedef uint32_t u32x2 __attribute__((ext_vector_type(2)));

#define DEVINL static __device__ __forceinline__
#define VMW(n) asm volatile("s_waitcnt vmcnt(" #n ")" ::: "memory")
#define LGK0() asm volatile("s_waitcnt lgkmcnt(0)" ::: "memory")
#define SB0() __builtin_amdgcn_sched_barrier(0)

DEVINL u16 f2bf(float f) {
  union { float f; u32 u; } x; x.f = f;
  u32 r = (x.u + 0x7fffu + ((x.u >> 16) & 1u)) >> 16;
  return (u16)r;
}
DEVINL float bflo(u32 x) { union { u32 u; float f; } t; t.u = x << 16; return t.f; }
DEVINL float bfhi(u32 x) { union { u32 u; float f; } t; t.u = x & 0xffff0000u; return t.f; }

DEVINL void gl_lds16(const u16* g, u16* l) {
  __builtin_amdgcn_global_load_lds(
      (const __attribute__((address_space(1))) u32*)(const void*)g,
      (__attribute__((address_space(3))) u32*)(void*)l, 16, 0, 0);
}

DEVINL f32x4 mfma16(bf16x8 a, bf16x8 b, f32x4 c) {
  return __builtin_amdgcn_mfma_f32_16x16x32_bf16(a, b, c, 0, 0, 0);
}

// ---------------- f32 -> bf16 convert (vectorized) ----------------
__global__ void k_cvt(const float* __restrict__ src, u16* __restrict__ dst, int n4) {
  int i = blockIdx.x * 256 + threadIdx.x;
  if (i >= n4) return;
  f32x4 v = ((const f32x4*)src)[i];
  u32x2 o;
  o[0] = (u32)f2bf(v[0]) | ((u32)f2bf(v[1]) << 16);
  o[1] = (u32)f2bf(v[2]) | ((u32)f2bf(v[3]) << 16);
  ((u32x2*)dst)[i] = o;
}

// ------- transpose + convert, 64x64 tiles, 16B stores: src(R x C) f32 -> dst(C x R) bf16
__global__ __launch_bounds__(256) void k_tcvt2(const float* __restrict__ src,
                                               u16* __restrict__ dst, int R, int C) {
  __shared__ float t[64][65];
  const int tid = threadIdx.x;
  const int r0 = blockIdx.y * 64, c0 = blockIdx.x * 64;
  {
    const int rr = tid >> 2, cg = (tid & 3) * 16;
    const float* s = src + (size_t)(r0 + rr) * C + c0 + cg;
#pragma unroll
    for (int i = 0; i < 4; ++i) {
      f32x4 v = *(const f32x4*)(s + 4 * i);
      t[rr][cg + 4 * i + 0] = v[0];
      t[rr][cg + 4 * i + 1] = v[1];
      t[rr][cg + 4 * i + 2] = v[2];
      t[rr][cg + 4 * i + 3] = v[3];
    }
  }
  __syncthreads();
  {
    const int rg = tid & 7, cb = tid >> 3;
#pragma unroll
    for (int it = 0; it < 2; ++it) {
      const int c = cb + it * 32;
      float v[8];
#pragma unroll
      for (int i = 0; i < 8; ++i) v[i] = t[rg * 8 + i][c];
      u32x4 o;
#pragma unroll
      for (int j = 0; j < 4; ++j)
        o[j] = (u32)f2bf(v[2 * j]) | ((u32)f2bf(v[2 * j + 1]) << 16);
      *(u32x4*)(dst + (size_t)(c0 + c) * R + r0 + rg * 8) = o;
    }
  }
}

// =================================================================
// QKV GEMM v2: 128M x 160N, grid 512 (2 blocks/CU), 4 waves = 2M x 2N.
// A: direct global->VGPR (ping-pong prefetch, compiler-tracked waits).
// B: LDS triple-buffered; ONE barrier + one counted vmcnt(13) per K-tile.
// =================================================================
__global__ __launch_bounds__(256, 2) void k_gemmq(
    const u16* __restrict__ A, const u16* __restrict__ Bgl, u16* __restrict__ Cout,
    const float* __restrict__ pb0, const float* __restrict__ pb1, const float* __restrict__ pb2)
{
  constexpr int K = 2880, NT = 45, LDC = 5120;
  __shared__ u16 Bsm[3][160 * 64];

  const int bid = blockIdx.x;
  const int swz = (bid & 7) * 64 + (bid >> 3);   // bijective, 512 % 8 == 0
  const int bx = swz >> 4, by = swz & 15;        // same-XCD blocks share bx
  const int m0 = by * 128, n0 = bx * 160;

  const int tid = threadIdx.x;
  const int w = tid >> 6, lane = tid & 63;
  const int l15 = lane & 15, lg = lane >> 4;
  const int wr = w >> 1, wc = w & 1;

  const u16* Bg = Bgl + (size_t)n0 * K;
  const u16* pA = A + (size_t)(m0 + wr * 64 + l15) * K + lg * 8;

  auto ld1 = [&](const u16* s, u16* d, int slot) {
    int row = slot >> 3, c = slot & 7;
    gl_lds16(s + (size_t)row * K + ((c ^ (row & 7)) << 3), d + row * 64 + c * 8);
  };
  auto stBa = [&](int tg) {      // rows {0-31, 80-111}
    u16* d = Bsm[tg % 3];
    const u16* s = Bg + tg * 64;
    ld1(s, d, tid); ld1(s, d, 640 + tid);
  };
  auto stBb = [&](int tg) {      // rows {32-79, 112-159}
    u16* d = Bsm[tg % 3];
    const u16* s = Bg + tg * 64;
    ld1(s, d, 256 + tid);
    ld1(s, d, (tid < 128) ? (512 + tid) : (768 + tid));
    ld1(s, d, 1024 + tid);
  };
  auto ldA = [&](int tg, int mh, bf16x8* dst) {  // fills dst[0..3] = m{0,1} x kk{0,1}
    const u16* p = pA + tg * 64;
#pragma unroll
    for (int m = 0; m < 2; ++m) {
      dst[m * 2 + 0] = *(const bf16x8*)(p + (size_t)(mh * 32 + m * 16) * K);
      dst[m * 2 + 1] = *(const bf16x8*)(p + (size_t)(mh * 32 + m * 16) * K + 32);
    }
  };

  const int rb = wc * 80 + l15;
  const int x0 = (lg ^ (l15 & 7)) << 3;
  const int x1 = x0 ^ 32;

  f32x4 acc[4][5] = {};
  bf16x8 afA[8], afB[8];

  // prologue (program order pinned): stB(0) | af(0) | stB(1) | vmcnt(13) forces stB(0)
  stBa(0); stBb(0);
  SB0();
  ldA(0, 0, afA + 0); ldA(0, 1, afA + 4);
  SB0();
  stBa(1); stBb(1);
  VMW(13);
  __builtin_amdgcn_s_barrier();
  SB0();

  auto tile = [&](int t, bf16x8 (&cur)[8], bf16x8 (&nxt)[8]) {
    const u16* Bb_ = Bsm[t % 3];
    const bool s2 = (t + 2 < NT), s1 = (t + 1 < NT);
    // ---- P1: ds_read n0-2; issue afA(t+1), stBa(t+2); MFMA m0-3 x n0-2
    {
      bf16x8 b0[3][2];
#pragma unroll
      for (int n = 0; n < 3; ++n) {
        b0[n][0] = *(const bf16x8*)&Bb_[(rb + n * 16) * 64 + x0];
        b0[n][1] = *(const bf16x8*)&Bb_[(rb + n * 16) * 64 + x1];
      }
      if (s1) ldA(t + 1, 0, nxt + 0);
      SB0();
      if (s2) stBa(t + 2);
      SB0();
      LGK0(); SB0();
      __builtin_amdgcn_s_setprio(1);
#pragma unroll
      for (int kk = 0; kk < 2; ++kk)
#pragma unroll
        for (int m = 0; m < 4; ++m)
#pragma unroll
          for (int n = 0; n < 3; ++n)
            acc[m][n] = mfma16(cur[m * 2 + kk], b0[n][kk], acc[m][n]);
      __builtin_amdgcn_s_setprio(0);
    }
    // ---- P2: ds_read n3-4; issue afB(t+1), stBb(t+2); MFMA; vmcnt(13); barrier
    {
      bf16x8 b1[2][2];
#pragma unroll
      for (int n = 0; n < 2; ++n) {
        b1[n][0] = *(const bf16x8*)&Bb_[(rb + 48 + n * 16) * 64 + x0];
        b1[n][1] = *(const bf16x8*)&Bb_[(rb + 48 + n * 16) * 64 + x1];
      }
      if (s1) ldA(t + 1, 1, nxt + 4);
      SB0();
      if (s2) stBb(t + 2);
      SB0();
      LGK0(); SB0();
      __builtin_amdgcn_s_setprio(1);
#pragma unroll
      for (int kk = 0; kk < 2; ++kk)
#pragma unroll
        for (int m = 0; m < 4; ++m)
#pragma unroll
          for (int n = 0; n < 2; ++n)
            acc[m][3 + n] = mfma16(cur[m * 2 + kk], b1[n][kk], acc[m][3 + n]);
      __builtin_amdgcn_s_setprio(0);
      if (s2) { VMW(13); } else if (s1) { VMW(8); } else { VMW(0); }
      __builtin_amdgcn_s_barrier();
      SB0();
    }
  };

  int t = 0;
  for (; t + 1 < NT; t += 2) { tile(t, afA, afB); tile(t + 1, afB, afA); }
  tile(NT - 1, afA, afB);  // NT = 45 (odd): current lives in afA

#pragma unroll
  for (int m2 = 0; m2 < 4; ++m2)
#pragma unroll
    for (int n = 0; n < 5; ++n) {
      int col = n0 + wc * 80 + n * 16 + l15;
      float bias = (col < 4096) ? pb0[col] : (col < 4608) ? pb1[col - 4096] : pb2[col - 4608];
#pragma unroll
      for (int q = 0; q < 4; ++q) {
        int row = m0 + wr * 64 + m2 * 16 + lg * 4 + q;
        Cout[(size_t)row * LDC + col] = f2bf(acc[m2][n][q] + bias);
      }
    }
}

// =================================================================
// Out-proj GEMM v2: 128M x 96N, grid 480; same A-direct + B triple-buffer.
// =================================================================
__global__ __launch_bounds__(256, 2) void k_gemmo(
    const u16* __restrict__ A, const u16* __restrict__ Bgl, float* __restrict__ Cout,
    const float* __restrict__ pb0)
{
  constexpr int K = 4096, NT = 64, LDC = 2880;
  __shared__ u16 Bsm[3][96 * 64];

  const int bid = blockIdx.x;
  const int swz = (bid & 7) * 60 + (bid >> 3);   // bijective, 480 % 8 == 0
  const int bx = swz / 16, by = swz & 15;
  const int m0 = by * 128, n0 = bx * 96;

  const int tid = threadIdx.x;
  const int w = tid >> 6, lane = tid & 63;
  const int l15 = lane & 15, lg = lane >> 4;
  const int wr = w >> 1, wc = w & 1;

  const u16* Bg = Bgl + (size_t)n0 * K;
  const u16* pA = A + (size_t)(m0 + wr * 64 + l15) * K + lg * 8;

  auto ld1 = [&](const u16* s, u16* d, int slot) {
    int row = slot >> 3, c = slot & 7;
    gl_lds16(s + (size_t)row * K + ((c ^ (row & 7)) << 3), d + row * 64 + c * 8);
  };
  auto stBa = [&](int tg) {   // rows 0-63
    u16* d = Bsm[tg % 3];
    const u16* s = Bg + tg * 64;
    ld1(s, d, tid); ld1(s, d, 256 + tid);
  };
  auto stBb = [&](int tg) {   // rows 64-95
    u16* d = Bsm[tg % 3];
    const u16* s = Bg + tg * 64;
    ld1(s, d, 512 + tid);
  };
  auto ldA = [&](int tg, int mh, bf16x8* dst) {
    const u16* p = pA + tg * 64;
#pragma unroll
    for (int m = 0; m < 2; ++m) {
      dst[m * 2 + 0] = *(const bf16x8*)(p + (size_t)(mh * 32 + m * 16) * K);
      dst[m * 2 + 1] = *(const bf16x8*)(p + (size_t)(mh * 32 + m * 16) * K + 32);
    }
  };

  const int rb = wc * 48 + l15;
  const int x0 = (lg ^ (l15 & 7)) << 3;
  const int x1 = x0 ^ 32;

  f32x4 acc[4][3] = {};
  bf16x8 afA[8], afB[8];

  stBa(0); stBb(0);
  SB0();
  ldA(0, 0, afA + 0); ldA(0, 1, afA + 4);
  SB0();
  stBa(1); stBb(1);
  VMW(11);  // newer than stBb(0): af0(8) + stBa1(2) + stBb1(1)
  __builtin_amdgcn_s_barrier();
  SB0();

  auto tile = [&](int t, bf16x8 (&cur)[8], bf16x8 (&nxt)[8]) {
    const u16* Bb_ = Bsm[t % 3];
    const bool s2 = (t + 2 < NT), s1 = (t + 1 < NT);
    // ---- P1: ds_read n0-1; issue afA(t+1), stBa(t+2); MFMA m0-3 x n0-1
    {
      bf16x8 b0[2][2];
#pragma unroll
      for (int n = 0; n < 2; ++n) {
        b0[n][0] = *(const bf16x8*)&Bb_[(rb + n * 16) * 64 + x0];
        b0[n][1] = *(const bf16x8*)&Bb_[(rb + n * 16) * 64 + x1];
      }
      if (s1) ldA(t + 1, 0, nxt + 0);
      SB0();
      if (s2) stBa(t + 2);
      SB0();
      LGK0(); SB0();
      __builtin_amdgcn_s_setprio(1);
#pragma unroll
      for (int kk = 0; kk < 2; ++kk)
#pragma unroll
        for (int m = 0; m < 4; ++m)
#pragma unroll
          for (int n = 0; n < 2; ++n)
            acc[m][n] = mfma16(cur[m * 2 + kk], b0[n][kk], acc[m][n]);
      __builtin_amdgcn_s_setprio(0);
    }
    // ---- P2: ds_read n2; issue afB(t+1), stBb(t+2); MFMA; vmcnt(11); barrier
    {
      bf16x8 b1[2];
      b1[0] = *(const bf16x8*)&Bb_[(rb + 32) * 64 + x0];
      b1[1] = *(const bf16x8*)&Bb_[(rb + 32) * 64 + x1];
      if (s1) ldA(t + 1, 1, nxt + 4);
      SB0();
      if (s2) stBb(t + 2);
      SB0();
      LGK0(); SB0();
      __builtin_amdgcn_s_setprio(1);
#pragma unroll
      for (int kk = 0; kk < 2; ++kk)
#pragma unroll
        for (int m = 0; m < 4; ++m)
          acc[m][2] = mfma16(cur[m * 2 + kk], b1[kk], acc[m][2]);
      __builtin_amdgcn_s_setprio(0);
      if (s2) { VMW(11); } else if (s1) { VMW(8); } else { VMW(0); }
      __builtin_amdgcn_s_barrier();
      SB0();
    }
  };

  for (int t = 0; t + 1 < NT; t += 2) { tile(t, afA, afB); tile(t + 1, afB, afA); }

#pragma unroll
  for (int m2 = 0; m2 < 4; ++m2)
#pragma unroll
    for (int n = 0; n < 3; ++n) {
      int col = n0 + wc * 48 + n * 16 + l15;
      float bias = pb0[col];
#pragma unroll
      for (int q = 0; q < 4; ++q) {
        int row = m0 + wr * 64 + m2 * 16 + lg * 4 + q;
        Cout[(size_t)row * LDC + col] = acc[m2][n][q] + bias;
      }
    }
}

// ---------------- in-place RoPE on QKV cols [0, 4608) ----------------
__global__ void k_rope(u16* __restrict__ qkv, const float* __restrict__ cosb,
                       const float* __restrict__ sinb) {
  int idx = blockIdx.x * 256 + threadIdx.x;
  if (idx >= 2048 * 72 * 4) return;
  int oct = idx & 3;
  int h = (idx >> 2) % 72;
  int s = idx / 288;
  u16* p1 = qkv + (size_t)s * 5120 + h * 64 + oct * 8;
  u16* p2 = p1 + 32;
  const float* pc = cosb + (size_t)s * 64 + oct * 8;
  const float* ps = sinb + (size_t)s * 64 + oct * 8;
  u32x4 a = *(const u32x4*)p1;
  u32x4 b = *(const u32x4*)p2;
  f32x4 c0 = *(const f32x4*)pc, c1 = *(const f32x4*)(pc + 4);
  f32x4 s0 = *(const f32x4*)ps, s1 = *(const f32x4*)(ps + 4);
  float C[8] = {c0[0], c0[1], c0[2], c0[3], c1[0], c1[1], c1[2], c1[3]};
  float Sn[8] = {s0[0], s0[1], s0[2], s0[3], s1[0], s1[1], s1[2], s1[3]};
  u32x4 ra, rb;
#pragma unroll
  for (int i = 0; i < 4; ++i) {
    float x1l = bflo(a[i]), x1h = bfhi(a[i]);
    float x2l = bflo(b[i]), x2h = bfhi(b[i]);
    float o1l = x1l * C[2 * i] - x2l * Sn[2 * i];
    float o1h = x1h * C[2 * i + 1] - x2h * Sn[2 * i + 1];
    float o2l = x2l * C[2 * i] + x1l * Sn[2 * i];
    float o2h = x2h * C[2 * i + 1] + x1h * Sn[2 * i + 1];
    ra[i] = (u32)f2bf(o1l) | ((u32)f2bf(o1h) << 16);
    rb[i] = (u32)f2bf(o2l) | ((u32)f2bf(o2h) << 16);
  }
  *(u32x4*)p1 = ra;
  *(u32x4*)p2 = rb;
}

// ---------------- sliding-window GQA attention with sinks ----------------
__global__ __launch_bounds__(512, 1) void k_attn(
    const u16* __restrict__ qkv, const float* __restrict__ sinks, u16* __restrict__ aout)
{
  __shared__ u16 Kl[192 * 64];
  __shared__ u16 Vt[64 * 200];
  __shared__ u16 Pl[8][2][16][40];

  const int qt = blockIdx.x * 64;
  const int kv = blockIdx.y;
  const int tid = threadIdx.x;
  const int w = tid >> 6, lane = tid & 63;
  const int l15 = lane & 15, lg = lane >> 4;

  for (int idx = tid; idx < 192 * 8; idx += 512) {
    int row = idx >> 3, ch = idx & 7;
    int key = qt - 128 + row;
    u32x4 val = {0, 0, 0, 0};
    if (key >= 0) val = *(const u32x4*)(qkv + (size_t)key * 5120 + 4096 + kv * 64 + ch * 8);
    *(u32x4*)((char*)Kl + row * 128 + ((ch * 16) ^ ((row & 7) << 4))) = val;
  }
  for (int idx = tid; idx < 192 * 8; idx += 512) {
    int row = idx >> 3, ch = idx & 7;
    int key = qt - 128 + row;
    u32x4 val = {0, 0, 0, 0};
    if (key >= 0) val = *(const u32x4*)(qkv + (size_t)key * 5120 + 4608 + kv * 64 + ch * 8);
    const u16* pv16 = (const u16*)&val;
#pragma unroll
    for (int j = 0; j < 8; ++j) Vt[(ch * 8 + j) * 200 + row] = pv16[j];
  }
  __syncthreads();

  const int h = kv * 8 + w;
  const float sink = sinks[h];

  for (int qs = 0; qs < 2; ++qs) {
    const int qb = qt + qs * 32;
    bf16x8 qf[2][2];
#pragma unroll
    for (int rt = 0; rt < 2; ++rt)
#pragma unroll
      for (int ks = 0; ks < 2; ++ks)
        qf[rt][ks] = *(const bf16x8*)(qkv + (size_t)(qb + rt * 16 + l15) * 5120 + h * 64 + ks * 32 + lg * 8);

    f32x4 S[2][5][2];
#pragma unroll
    for (int kb = 0; kb < 5; ++kb)
#pragma unroll
      for (int hh = 0; hh < 2; ++hh) {
        int krow = qs * 32 + kb * 32 + hh * 16 + l15;
        int sw = (krow & 7) << 4;
        bf16x8 kf0 = *(const bf16x8*)((const char*)Kl + krow * 128 + ((lg * 16) ^ sw));
        bf16x8 kf1 = *(const bf16x8*)((const char*)Kl + krow * 128 + ((64 + lg * 16) ^ sw));
#pragma unroll
        for (int rt = 0; rt < 2; ++rt) {
          f32x4 a = {0.f, 0.f, 0.f, 0.f};
          a = mfma16(qf[rt][0], kf0, a);
          a = mfma16(qf[rt][1], kf1, a);
          S[rt][kb][hh] = a;
        }
      }

    float inv_s[2][4];
#pragma unroll
    for (int rt = 0; rt < 2; ++rt)
#pragma unroll
      for (int r = 0; r < 4; ++r) {
        int q_abs = qb + rt * 16 + lg * 4 + r;
        float m = -1e30f;
#pragma unroll
        for (int kb = 0; kb < 5; ++kb)
#pragma unroll
          for (int hh = 0; hh < 2; ++hh) {
            int k_abs = qb - 128 + kb * 32 + hh * 16 + l15;
            float v = S[rt][kb][hh][r] * 0.125f;
            bool ok = (k_abs >= 0) && (k_abs <= q_abs) && (q_abs - k_abs < 128);
            v = ok ? v : -1e30f;
            S[rt][kb][hh][r] = v;
            m = fmaxf(m, v);
          }
        m = fmaxf(m, __shfl_xor(m, 1, 64));
        m = fmaxf(m, __shfl_xor(m, 2, 64));
        m = fmaxf(m, __shfl_xor(m, 4, 64));
        m = fmaxf(m, __shfl_xor(m, 8, 64));
        m = fmaxf(m, sink);
        float sum = 0.f;
#pragma unroll
        for (int kb = 0; kb < 5; ++kb)
#pragma unroll
          for (int hh = 0; hh < 2; ++hh) {
            float p = __expf(S[rt][kb][hh][r] - m);
            S[rt][kb][hh][r] = p;
            sum += p;
          }
        sum += __shfl_xor(sum, 1, 64);
        sum += __shfl_xor(sum, 2, 64);
        sum += __shfl_xor(sum, 4, 64);
        sum += __shfl_xor(sum, 8, 64);
        inv_s[rt][r] = 1.0f / (sum + __expf(sink - m));
      }

    f32x4 pv[2][4] = {};
#pragma unroll
    for (int kb = 0; kb < 5; ++kb) {
      asm volatile("s_waitcnt lgkmcnt(0)" ::: "memory");
#pragma unroll
      for (int rt = 0; rt < 2; ++rt)
#pragma unroll
        for (int hh = 0; hh < 2; ++hh)
#pragma unroll
          for (int r = 0; r < 4; ++r)
            Pl[w][rt][lg * 4 + r][hh * 16 + l15] = f2bf(S[rt][kb][hh][r] * inv_s[rt][r]);
      asm volatile("s_waitcnt lgkmcnt(0)" ::: "memory");
      __builtin_amdgcn_sched_barrier(0);
      bf16x8 a0 = *(const bf16x8*)&Pl[w][0][l15][lg * 8];
      bf16x8 a1 = *(const bf16x8*)&Pl[w][1][l15][lg * 8];
#pragma unroll
      for (int nt = 0; nt < 4; ++nt) {
        bf16x8 vf = *(const bf16x8*)&Vt[(nt * 16 + l15) * 200 + qs * 32 + kb * 32 + lg * 8];
        pv[0][nt] = mfma16(a0, vf, pv[0][nt]);
        pv[1][nt] = mfma16(a1, vf, pv[1][nt]);
      }
    }

#pragma unroll
    for (int rt = 0; rt < 2; ++rt)
#pragma unroll
      for (int nt = 0; nt < 4; ++nt)
#pragma unroll
        for (int r = 0; r < 4; ++r)
          aout[(size_t)(qb + rt * 16 + lg * 4 + r) * 4096 + h * 64 + nt * 16 + l15] =
              f2bf(pv[rt][nt][r]);
  }
}

extern "C" void kernel_launch(void* const* d_in, const int* in_sizes, int n_in,
                              void* d_out, int out_size, void* d_ws, size_t ws_size,
                              hipStream_t stream) {
  const float* hs    = (const float*)d_in[0];
  const float* cosb  = (const float*)d_in[1];
  const float* sinb  = (const float*)d_in[2];
  const float* Wq    = (const float*)d_in[3];
  const float* bq    = (const float*)d_in[4];
  const float* Wk    = (const float*)d_in[5];
  const float* bk    = (const float*)d_in[6];
  const float* Wv    = (const float*)d_in[7];
  const float* bv    = (const float*)d_in[8];
  const float* Wo    = (const float*)d_in[9];
  const float* bo    = (const float*)d_in[10];
  const float* sinks = (const float*)d_in[11];

  char* ws = (char*)d_ws;
  u16* hsb   = (u16*)ws;  ws += (size_t)2048 * 2880 * 2;
  u16* WqkvT = (u16*)ws;  ws += (size_t)5120 * 2880 * 2;
  u16* WoT   = (u16*)ws;  ws += (size_t)2880 * 4096 * 2;
  u16* QKV   = (u16*)ws;  ws += (size_t)2048 * 5120 * 2;
  u16* AOut  = (u16*)ws;  ws += (size_t)2048 * 4096 * 2;

  k_cvt<<<5760, 256, 0, stream>>>(hs, hsb, 1474560);
  k_tcvt2<<<dim3(4096 / 64, 2880 / 64), 256, 0, stream>>>(Wq, WqkvT, 2880, 4096);
  k_tcvt2<<<dim3(512 / 64, 2880 / 64), 256, 0, stream>>>(Wk, WqkvT + (size_t)4096 * 2880, 2880, 512);
  k_tcvt2<<<dim3(512 / 64, 2880 / 64), 256, 0, stream>>>(Wv, WqkvT + (size_t)4608 * 2880, 2880, 512);
  k_tcvt2<<<dim3(2880 / 64, 4096 / 64), 256, 0, stream>>>(Wo, WoT, 4096, 2880);

  k_gemmq<<<512, 256, 0, stream>>>(hsb, WqkvT, QKV, bq, bk, bv);

  k_rope<<<2304, 256, 0, stream>>>(QKV, cosb, sinb);

  k_attn<<<dim3(32, 8), 512, 0, stream>>>(QKV, sinks, AOut);

  k_gemmo<<<480, 256, 0, stream>>>(AOut, WoT, (float*)d_out, bo);
}

// Round 7
// 167.847 us; speedup vs baseline: 1.7942x; 1.7942x over previous
//
#include <hip/hip_runtime.h>
#include <stdint.h>
#include <stddef.h>

typedef unsigned short u16;
typedef unsigned int u32;
typedef float f32x4 __attribute__((ext_vector_type(4)));
typedef __bf16 bf16x8 __attribute__((ext_vector_type(8)));
typedef uint32_t u32x4 __attribute__((ext_vector_type(4)));
typedef uint32_t u32x2 __attribute__((ext_vector_type(2)));

#define DEVINL static __device__ __forceinline__
#define VMW(n) asm volatile("s_waitcnt vmcnt(" #n ")" ::: "memory")
#define LGK0() asm volatile("s_waitcnt lgkmcnt(0)" ::: "memory")
#define SB0() __builtin_amdgcn_sched_barrier(0)

DEVINL u16 f2bf(float f) {
  union { float f; u32 u; } x; x.f = f;
  u32 r = (x.u + 0x7fffu + ((x.u >> 16) & 1u)) >> 16;
  return (u16)r;
}
DEVINL float bflo(u32 x) { union { u32 u; float f; } t; t.u = x << 16; return t.f; }
DEVINL float bfhi(u32 x) { union { u32 u; float f; } t; t.u = x & 0xffff0000u; return t.f; }

DEVINL void gl_lds16(const u16* g, u16* l) {
  __builtin_amdgcn_global_load_lds(
      (const __attribute__((address_space(1))) u32*)(const void*)g,
      (__attribute__((address_space(3))) u32*)(void*)l, 16, 0, 0);
}

DEVINL f32x4 mfma16(bf16x8 a, bf16x8 b, f32x4 c) {
  return __builtin_amdgcn_mfma_f32_16x16x32_bf16(a, b, c, 0, 0, 0);
}

// rope one (v1,v2) = dims (d..d+7, d+32..d+39) pair given cos/sin[8] for d..d+7
DEVINL void rope8(u32x4& v1, u32x4& v2, const float* pc, const float* ps) {
  f32x4 c0 = *(const f32x4*)pc, c1 = *(const f32x4*)(pc + 4);
  f32x4 s0 = *(const f32x4*)ps, s1 = *(const f32x4*)(ps + 4);
  float C[8] = {c0[0], c0[1], c0[2], c0[3], c1[0], c1[1], c1[2], c1[3]};
  float Sn[8] = {s0[0], s0[1], s0[2], s0[3], s1[0], s1[1], s1[2], s1[3]};
  u32x4 r1, r2;
#pragma unroll
  for (int i = 0; i < 4; ++i) {
    float x1l = bflo(v1[i]), x1h = bfhi(v1[i]);
    float x2l = bflo(v2[i]), x2h = bfhi(v2[i]);
    float o1l = x1l * C[2 * i] - x2l * Sn[2 * i];
    float o1h = x1h * C[2 * i + 1] - x2h * Sn[2 * i + 1];
    float o2l = x2l * C[2 * i] + x1l * Sn[2 * i];
    float o2h = x2h * C[2 * i + 1] + x1h * Sn[2 * i + 1];
    r1[i] = (u32)f2bf(o1l) | ((u32)f2bf(o1h) << 16);
    r2[i] = (u32)f2bf(o2l) | ((u32)f2bf(o2h) << 16);
  }
  v1 = r1; v2 = r2;
}

// =================================================================
// Fused preprocessing: [0,5760) cvt hs; then 4 transpose-convert segments.
// =================================================================
__global__ __launch_bounds__(256) void k_pre(
    const float* __restrict__ hs, u16* __restrict__ hsb,
    const float* __restrict__ Wq, const float* __restrict__ Wk,
    const float* __restrict__ Wv, const float* __restrict__ Wo,
    u16* __restrict__ WqkvT, u16* __restrict__ WoT)
{
  __shared__ float t[64][65];
  int id = blockIdx.x;
  const int tid = threadIdx.x;
  if (id < 5760) {  // ---- cvt: 5760*256 = 1,474,560 f32x4 exactly
    int i = id * 256 + tid;
    f32x4 v = ((const f32x4*)hs)[i];
    u32x2 o;
    o[0] = (u32)f2bf(v[0]) | ((u32)f2bf(v[1]) << 16);
    o[1] = (u32)f2bf(v[2]) | ((u32)f2bf(v[3]) << 16);
    ((u32x2*)hsb)[i] = o;
    return;
  }
  id -= 5760;
  const float* src; u16* dst; int R, C, bx, by;
  if (id < 2880)       { src = Wq; dst = WqkvT;                         R = 2880; C = 4096; bx = id & 63; by = id >> 6; }
  else if (id < 3240)  { id -= 2880; src = Wk; dst = WqkvT + (size_t)4096 * 2880; R = 2880; C = 512;  bx = id & 7;  by = id >> 3; }
  else if (id < 3600)  { id -= 3240; src = Wv; dst = WqkvT + (size_t)4608 * 2880; R = 2880; C = 512;  bx = id & 7;  by = id >> 3; }
  else                 { id -= 3600; src = Wo; dst = WoT;               R = 4096; C = 2880; bx = id % 45; by = id / 45; }
  const int r0 = by * 64, c0 = bx * 64;
  {
    const int rr = tid >> 2, cg = (tid & 3) * 16;
    const float* s = src + (size_t)(r0 + rr) * C + c0 + cg;
#pragma unroll
    for (int i = 0; i < 4; ++i) {
      f32x4 v = *(const f32x4*)(s + 4 * i);
      t[rr][cg + 4 * i + 0] = v[0];
      t[rr][cg + 4 * i + 1] = v[1];
      t[rr][cg + 4 * i + 2] = v[2];
      t[rr][cg + 4 * i + 3] = v[3];
    }
  }
  __syncthreads();
  {
    const int rg = tid & 7, cb = tid >> 3;
#pragma unroll
    for (int it = 0; it < 2; ++it) {
      const int c = cb + it * 32;
      float v[8];
#pragma unroll
      for (int i = 0; i < 8; ++i) v[i] = t[rg * 8 + i][c];
      u32x4 o;
#pragma unroll
      for (int j = 0; j < 4; ++j)
        o[j] = (u32)f2bf(v[2 * j]) | ((u32)f2bf(v[2 * j + 1]) << 16);
      *(u32x4*)(dst + (size_t)(c0 + c) * R + r0 + rg * 8) = o;
    }
  }
}

// =================================================================
// QKV GEMM (round-5 validated): 128M x 160N, grid 512 (2 blocks/CU),
// 4 waves = 2M x 2N, 4 phases, 2 barriers/K-tile, VM(5)@P2 / VM(2)@P4.
// =================================================================
__global__ __launch_bounds__(256, 2) void k_gemmq(
    const u16* __restrict__ A, const u16* __restrict__ Bgl, u16* __restrict__ Cout,
    const float* __restrict__ pb0, const float* __restrict__ pb1, const float* __restrict__ pb2)
{
  constexpr int K = 2880, NT = 45, LDC = 5120;
  __shared__ u16 Asm[2][128 * 64];
  __shared__ u16 Bsm[2][160 * 64];

  const int bid = blockIdx.x;
  const int swz = (bid & 7) * 64 + (bid >> 3);
  const int bx = swz >> 4, by = swz & 15;
  const int m0 = by * 128, n0 = bx * 160;

  const int tid = threadIdx.x;
  const int w = tid >> 6, lane = tid & 63;
  const int l15 = lane & 15, lg = lane >> 4;
  const int wr = w >> 1, wc = w & 1;

  const u16* Ag = A + (size_t)m0 * K;
  const u16* Bg = Bgl + (size_t)n0 * K;

  auto ld1 = [&](const u16* s, u16* d, int slot) {
    int row = slot >> 3, c = slot & 7;
    gl_lds16(s + (size_t)row * K + ((c ^ (row & 7)) << 3), d + row * 64 + c * 8);
  };
  auto stApart = [&](int tg, int part) {
    u16* d = Asm[tg & 1];
    const u16* s = Ag + tg * 64;
    ld1(s, d, part * 256 + tid);
    ld1(s, d, part * 256 + 512 + tid);
  };
  auto stBa = [&](int tg) {
    u16* d = Bsm[tg & 1];
    const u16* s = Bg + tg * 64;
    ld1(s, d, tid);
    ld1(s, d, 640 + tid);
  };
  auto stBb = [&](int tg) {
    u16* d = Bsm[tg & 1];
    const u16* s = Bg + tg * 64;
    ld1(s, d, 256 + tid);
    ld1(s, d, (tid < 128) ? (512 + tid) : (768 + tid));
    ld1(s, d, 1024 + tid);
  };

  const int ra = wr * 64 + l15;
  const int rb = wc * 80 + l15;
  const int x0 = (lg ^ (l15 & 7)) << 3;
  const int x1 = x0 ^ 32;

  f32x4 acc[4][5] = {};
  bf16x8 af[2][2], bfr[5][2];

  stBa(0); stBb(0); stApart(0, 0); stApart(0, 1);
  VMW(2);
  __builtin_amdgcn_s_barrier();
  SB0();

  for (int t = 0; t < NT; ++t) {
    const u16* Ab = Asm[t & 1];
    const u16* Bb_ = Bsm[t & 1];
    const bool st = (t + 1 < NT);
    // ---- P1: read A m01 + B n01; stage Ba(t+1)
#pragma unroll
    for (int m = 0; m < 2; ++m) {
      af[m][0] = *(const bf16x8*)&Ab[(ra + m * 16) * 64 + x0];
      af[m][1] = *(const bf16x8*)&Ab[(ra + m * 16) * 64 + x1];
    }
#pragma unroll
    for (int n = 0; n < 2; ++n) {
      bfr[n][0] = *(const bf16x8*)&Bb_[(rb + n * 16) * 64 + x0];
      bfr[n][1] = *(const bf16x8*)&Bb_[(rb + n * 16) * 64 + x1];
    }
    if (st) stBa(t + 1);
    LGK0(); SB0();
    __builtin_amdgcn_s_setprio(1);
#pragma unroll
    for (int kk = 0; kk < 2; ++kk)
#pragma unroll
      for (int m = 0; m < 2; ++m)
#pragma unroll
        for (int n = 0; n < 2; ++n)
          acc[m][n] = mfma16(af[m][kk], bfr[n][kk], acc[m][n]);
    __builtin_amdgcn_s_setprio(0);
    // ---- P2: read B n234; stage Bb(t+1); VM(5); barrier
#pragma unroll
    for (int n = 2; n < 5; ++n) {
      bfr[n][0] = *(const bf16x8*)&Bb_[(rb + n * 16) * 64 + x0];
      bfr[n][1] = *(const bf16x8*)&Bb_[(rb + n * 16) * 64 + x1];
    }
    if (st) stBb(t + 1);
    LGK0(); SB0();
    __builtin_amdgcn_s_setprio(1);
#pragma unroll
    for (int kk = 0; kk < 2; ++kk)
#pragma unroll
      for (int m = 0; m < 2; ++m)
#pragma unroll
        for (int n = 2; n < 5; ++n)
          acc[m][n] = mfma16(af[m][kk], bfr[n][kk], acc[m][n]);
    __builtin_amdgcn_s_setprio(0);
    if (st) { VMW(5); } else { VMW(0); }
    __builtin_amdgcn_s_barrier();
    SB0();
    // ---- P3: read A m23; stage Ap1(t+1)
#pragma unroll
    for (int m = 0; m < 2; ++m) {
      af[m][0] = *(const bf16x8*)&Ab[(ra + 32 + m * 16) * 64 + x0];
      af[m][1] = *(const bf16x8*)&Ab[(ra + 32 + m * 16) * 64 + x1];
    }
    if (st) stApart(t + 1, 0);
    LGK0(); SB0();
    __builtin_amdgcn_s_setprio(1);
#pragma unroll
    for (int kk = 0; kk < 2; ++kk)
#pragma unroll
      for (int m = 0; m < 2; ++m)
#pragma unroll
        for (int n = 0; n < 2; ++n)
          acc[2 + m][n] = mfma16(af[m][kk], bfr[n][kk], acc[2 + m][n]);
    __builtin_amdgcn_s_setprio(0);
    // ---- P4: stage Ap2(t+1); VM(2); barrier
    if (st) stApart(t + 1, 1);
    __builtin_amdgcn_s_setprio(1);
#pragma unroll
    for (int kk = 0; kk < 2; ++kk)
#pragma unroll
      for (int m = 0; m < 2; ++m)
#pragma unroll
        for (int n = 2; n < 5; ++n)
          acc[2 + m][n] = mfma16(af[m][kk], bfr[n][kk], acc[2 + m][n]);
    __builtin_amdgcn_s_setprio(0);
    VMW(2);
    __builtin_amdgcn_s_barrier();
    SB0();
  }

#pragma unroll
  for (int m2 = 0; m2 < 4; ++m2)
#pragma unroll
    for (int n = 0; n < 5; ++n) {
      int col = n0 + wc * 80 + n * 16 + l15;
      float bias = (col < 4096) ? pb0[col] : (col < 4608) ? pb1[col - 4096] : pb2[col - 4608];
#pragma unroll
      for (int q = 0; q < 4; ++q) {
        int row = m0 + wr * 64 + m2 * 16 + lg * 4 + q;
        Cout[(size_t)row * LDC + col] = f2bf(acc[m2][n][q] + bias);
      }
    }
}

// =================================================================
// Out-proj GEMM (round-5 validated): 128M x 96N, grid 480.
// =================================================================
__global__ __launch_bounds__(256, 2) void k_gemmo(
    const u16* __restrict__ A, const u16* __restrict__ Bgl, float* __restrict__ Cout,
    const float* __restrict__ pb0)
{
  constexpr int K = 4096, NT = 64, LDC = 2880;
  __shared__ u16 Asm[2][128 * 64];
  __shared__ u16 Bsm[2][96 * 64];

  const int bid = blockIdx.x;
  const int swz = (bid & 7) * 60 + (bid >> 3);
  const int bx = swz / 16, by = swz & 15;
  const int m0 = by * 128, n0 = bx * 96;

  const int tid = threadIdx.x;
  const int w = tid >> 6, lane = tid & 63;
  const int l15 = lane & 15, lg = lane >> 4;
  const int wr = w >> 1, wc = w & 1;

  const u16* Ag = A + (size_t)m0 * K;
  const u16* Bg = Bgl + (size_t)n0 * K;

  auto ld1 = [&](const u16* s, u16* d, int slot) {
    int row = slot >> 3, c = slot & 7;
    gl_lds16(s + (size_t)row * K + ((c ^ (row & 7)) << 3), d + row * 64 + c * 8);
  };
  auto stApart = [&](int tg, int part) {
    u16* d = Asm[tg & 1];
    const u16* s = Ag + tg * 64;
    ld1(s, d, part * 256 + tid);
    ld1(s, d, part * 256 + 512 + tid);
  };
  auto stB = [&](int tg) {
    u16* d = Bsm[tg & 1];
    const u16* s = Bg + tg * 64;
    ld1(s, d, tid);
    ld1(s, d, 256 + tid);
    ld1(s, d, 512 + tid);
  };

  const int ra = wr * 64 + l15;
  const int rb = wc * 48 + l15;
  const int x0 = (lg ^ (l15 & 7)) << 3;
  const int x1 = x0 ^ 32;

  f32x4 acc[4][3] = {};
  bf16x8 af[2][2], bfr[3][2];

  stB(0); stApart(0, 0); stApart(0, 1);
  VMW(2);
  __builtin_amdgcn_s_barrier();
  SB0();

  for (int t = 0; t < NT; ++t) {
    const u16* Ab = Asm[t & 1];
    const u16* Bb_ = Bsm[t & 1];
    const bool st = (t + 1 < NT);
    // ---- P1
#pragma unroll
    for (int m = 0; m < 2; ++m) {
      af[m][0] = *(const bf16x8*)&Ab[(ra + m * 16) * 64 + x0];
      af[m][1] = *(const bf16x8*)&Ab[(ra + m * 16) * 64 + x1];
    }
#pragma unroll
    for (int n = 0; n < 3; ++n) {
      bfr[n][0] = *(const bf16x8*)&Bb_[(rb + n * 16) * 64 + x0];
      bfr[n][1] = *(const bf16x8*)&Bb_[(rb + n * 16) * 64 + x1];
    }
    if (st) { stB(t + 1); stApart(t + 1, 0); }
    LGK0(); SB0();
    __builtin_amdgcn_s_setprio(1);
#pragma unroll
    for (int kk = 0; kk < 2; ++kk)
#pragma unroll
      for (int m = 0; m < 2; ++m)
#pragma unroll
        for (int n = 0; n < 3; ++n)
          acc[m][n] = mfma16(af[m][kk], bfr[n][kk], acc[m][n]);
    __builtin_amdgcn_s_setprio(0);
    if (st) { VMW(5); } else { VMW(0); }
    __builtin_amdgcn_s_barrier();
    SB0();
    // ---- P2
#pragma unroll
    for (int m = 0; m < 2; ++m) {
      af[m][0] = *(const bf16x8*)&Ab[(ra + 32 + m * 16) * 64 + x0];
      af[m][1] = *(const bf16x8*)&Ab[(ra + 32 + m * 16) * 64 + x1];
    }
    if (st) stApart(t + 1, 1);
    LGK0(); SB0();
    __builtin_amdgcn_s_setprio(1);
#pragma unroll
    for (int kk = 0; kk < 2; ++kk)
#pragma unroll
      for (int m = 0; m < 2; ++m)
#pragma unroll
        for (int n = 0; n < 3; ++n)
          acc[2 + m][n] = mfma16(af[m][kk], bfr[n][kk], acc[2 + m][n]);
    __builtin_amdgcn_s_setprio(0);
    VMW(2);
    __builtin_amdgcn_s_barrier();
    SB0();
  }

#pragma unroll
  for (int m2 = 0; m2 < 4; ++m2)
#pragma unroll
    for (int n = 0; n < 3; ++n) {
      int col = n0 + wc * 48 + n * 16 + l15;
      float bias = pb0[col];
#pragma unroll
      for (int q = 0; q < 4; ++q) {
        int row = m0 + wr * 64 + m2 * 16 + lg * 4 + q;
        Cout[(size_t)row * LDC + col] = acc[m2][n][q] + bias;
      }
    }
}

// ---------------- sliding-window GQA attention, RoPE fused, sinks ----------------
// grid (S/64, NKV); block 512 = 8 waves = 8 q-heads; two 32-q subtiles/wave.
__global__ __launch_bounds__(512, 1) void k_attn(
    const u16* __restrict__ qkv, const float* __restrict__ sinks,
    const float* __restrict__ cosb, const float* __restrict__ sinb,
    u16* __restrict__ aout)
{
  __shared__ u16 Kl[192 * 64];
  __shared__ u16 Vt[64 * 200];
  __shared__ u16 Pl[8][2][16][40];

  const int qt = blockIdx.x * 64;
  const int kv = blockIdx.y;
  const int tid = threadIdx.x;
  const int w = tid >> 6, lane = tid & 63;
  const int l15 = lane & 15, lg = lane >> 4;

  // stage K with fused RoPE: 192 rows x 4 ch-pairs
  for (int idx = tid; idx < 192 * 4; idx += 512) {
    int row = idx >> 2, ch = idx & 3;
    int key = qt - 128 + row;
    u32x4 v1 = {0, 0, 0, 0}, v2 = {0, 0, 0, 0};
    if (key >= 0) {
      const u16* p = qkv + (size_t)key * 5120 + 4096 + kv * 64 + ch * 8;
      v1 = *(const u32x4*)p;
      v2 = *(const u32x4*)(p + 32);
      rope8(v1, v2, cosb + (size_t)key * 64 + ch * 8, sinb + (size_t)key * 64 + ch * 8);
    }
    int sw = (row & 7) << 4;
    *(u32x4*)((char*)Kl + row * 128 + ((ch * 16) ^ sw)) = v1;
    *(u32x4*)((char*)Kl + row * 128 + (((ch + 4) * 16) ^ sw)) = v2;
  }
  // stage V transposed (no rope)
  for (int idx = tid; idx < 192 * 8; idx += 512) {
    int row = idx >> 3, ch = idx & 7;
    int key = qt - 128 + row;
    u32x4 val = {0, 0, 0, 0};
    if (key >= 0) val = *(const u32x4*)(qkv + (size_t)key * 5120 + 4608 + kv * 64 + ch * 8);
    const u16* pv16 = (const u16*)&val;
#pragma unroll
    for (int j = 0; j < 8; ++j) Vt[(ch * 8 + j) * 200 + row] = pv16[j];
  }
  __syncthreads();

  const int h = kv * 8 + w;
  const float sink = sinks[h];

  for (int qs = 0; qs < 2; ++qs) {
    const int qb = qt + qs * 32;
    bf16x8 qf[2][2];
#pragma unroll
    for (int rt = 0; rt < 2; ++rt) {
      const int qrow = qb + rt * 16 + l15;
      const u16* p = qkv + (size_t)qrow * 5120 + h * 64 + lg * 8;
      union { u32x4 u; bf16x8 v; } a, b;
      a.u = *(const u32x4*)p;
      b.u = *(const u32x4*)(p + 32);
      rope8(a.u, b.u, cosb + (size_t)qrow * 64 + lg * 8, sinb + (size_t)qrow * 64 + lg * 8);
      qf[rt][0] = a.v;
      qf[rt][1] = b.v;
    }

    f32x4 S[2][5][2];
#pragma unroll
    for (int kb = 0; kb < 5; ++kb)
#pragma unroll
      for (int hh = 0; hh < 2; ++hh) {
        int krow = qs * 32 + kb * 32 + hh * 16 + l15;
        int sw = (krow & 7) << 4;
        bf16x8 kf0 = *(const bf16x8*)((const char*)Kl + krow * 128 + ((lg * 16) ^ sw));
        bf16x8 kf1 = *(const bf16x8*)((const char*)Kl + krow * 128 + ((64 + lg * 16) ^ sw));
#pragma unroll
        for (int rt = 0; rt < 2; ++rt) {
          f32x4 a = {0.f, 0.f, 0.f, 0.f};
          a = mfma16(qf[rt][0], kf0, a);
          a = mfma16(qf[rt][1], kf1, a);
          S[rt][kb][hh] = a;
        }
      }

    float inv_s[2][4];
#pragma unroll
    for (int rt = 0; rt < 2; ++rt)
#pragma unroll
      for (int r = 0; r < 4; ++r) {
        int q_abs = qb + rt * 16 + lg * 4 + r;
        float m = -1e30f;
#pragma unroll
        for (int kb = 0; kb < 5; ++kb)
#pragma unroll
          for (int hh = 0; hh < 2; ++hh) {
            int k_abs = qb - 128 + kb * 32 + hh * 16 + l15;
            float v = S[rt][kb][hh][r] * 0.125f;
            bool ok = (k_abs >= 0) && (k_abs <= q_abs) && (q_abs - k_abs < 128);
            v = ok ? v : -1e30f;
            S[rt][kb][hh][r] = v;
            m = fmaxf(m, v);
          }
        m = fmaxf(m, __shfl_xor(m, 1, 64));
        m = fmaxf(m, __shfl_xor(m, 2, 64));
        m = fmaxf(m, __shfl_xor(m, 4, 64));
        m = fmaxf(m, __shfl_xor(m, 8, 64));
        m = fmaxf(m, sink);
        float sum = 0.f;
#pragma unroll
        for (int kb = 0; kb < 5; ++kb)
#pragma unroll
          for (int hh = 0; hh < 2; ++hh) {
            float p = __expf(S[rt][kb][hh][r] - m);
            S[rt][kb][hh][r] = p;
            sum += p;
          }
        sum += __shfl_xor(sum, 1, 64);
        sum += __shfl_xor(sum, 2, 64);
        sum += __shfl_xor(sum, 4, 64);
        sum += __shfl_xor(sum, 8, 64);
        inv_s[rt][r] = 1.0f / (sum + __expf(sink - m));
      }

    f32x4 pv[2][4] = {};
#pragma unroll
    for (int kb = 0; kb < 5; ++kb) {
      asm volatile("s_waitcnt lgkmcnt(0)" ::: "memory");
#pragma unroll
      for (int rt = 0; rt < 2; ++rt)
#pragma unroll
        for (int hh = 0; hh < 2; ++hh)
#pragma unroll
          for (int r = 0; r < 4; ++r)
            Pl[w][rt][lg * 4 + r][hh * 16 + l15] = f2bf(S[rt][kb][hh][r] * inv_s[rt][r]);
      asm volatile("s_waitcnt lgkmcnt(0)" ::: "memory");
      __builtin_amdgcn_sched_barrier(0);
      bf16x8 a0 = *(const bf16x8*)&Pl[w][0][l15][lg * 8];
      bf16x8 a1 = *(const bf16x8*)&Pl[w][1][l15][lg * 8];
#pragma unroll
      for (int nt = 0; nt < 4; ++nt) {
        bf16x8 vf = *(const bf16x8*)&Vt[(nt * 16 + l15) * 200 + qs * 32 + kb * 32 + lg * 8];
        pv[0][nt] = mfma16(a0, vf, pv[0][nt]);
        pv[1][nt] = mfma16(a1, vf, pv[1][nt]);
      }
    }

#pragma unroll
    for (int rt = 0; rt < 2; ++rt)
#pragma unroll
      for (int nt = 0; nt < 4; ++nt)
#pragma unroll
        for (int r = 0; r < 4; ++r)
          aout[(size_t)(qb + rt * 16 + lg * 4 + r) * 4096 + h * 64 + nt * 16 + l15] =
              f2bf(pv[rt][nt][r]);
  }
}

extern "C" void kernel_launch(void* const* d_in, const int* in_sizes, int n_in,
                              void* d_out, int out_size, void* d_ws, size_t ws_size,
                              hipStream_t stream) {
  const float* hs    = (const float*)d_in[0];
  const float* cosb  = (const float*)d_in[1];
  const float* sinb  = (const float*)d_in[2];
  const float* Wq    = (const float*)d_in[3];
  const float* bq    = (const float*)d_in[4];
  const float* Wk    = (const float*)d_in[5];
  const float* bk    = (const float*)d_in[6];
  const float* Wv    = (const float*)d_in[7];
  const float* bv    = (const float*)d_in[8];
  const float* Wo    = (const float*)d_in[9];
  const float* bo    = (const float*)d_in[10];
  const float* sinks = (const float*)d_in[11];

  char* ws = (char*)d_ws;
  u16* hsb   = (u16*)ws;  ws += (size_t)2048 * 2880 * 2;
  u16* WqkvT = (u16*)ws;  ws += (size_t)5120 * 2880 * 2;
  u16* WoT   = (u16*)ws;  ws += (size_t)2880 * 4096 * 2;
  u16* QKV   = (u16*)ws;  ws += (size_t)2048 * 5120 * 2;
  u16* AOut  = (u16*)ws;  ws += (size_t)2048 * 4096 * 2;

  k_pre<<<12240, 256, 0, stream>>>(hs, hsb, Wq, Wk, Wv, Wo, WqkvT, WoT);

  k_gemmq<<<512, 256, 0, stream>>>(hsb, WqkvT, QKV, bq, bk, bv);

  k_attn<<<dim3(32, 8), 512, 0, stream>>>(QKV, sinks, cosb, sinb, AOut);

  k_gemmo<<<480, 256, 0, stream>>>(AOut, WoT, (float*)d_out, bo);
}